// Round 9
// baseline (634.543 us; speedup 1.0000x reference)
//
#include <hip/hip_runtime.h>

#define CIN  32
#define COUT 64
#define PP   1024
#define NN   24
#define NA   60
#define KS   4
#define PA   (PP*NA)          // 61440
#define CK   (CIN*KS)         // 128
#define FKLD 136              // padded LDS row stride in shorts (272 B)
constexpr float SIGMA_INV = 12.5f;   // 1/0.08
constexpr float EPS = 1e-5f;

typedef __attribute__((ext_vector_type(8))) short short8;
typedef __attribute__((ext_vector_type(4))) float floatx4;

__device__ inline unsigned f2bf1(float f) {   // RTNE to bf16, as unsigned
    unsigned u = __float_as_uint(f);
    return (u + 0x7fffu + ((u >> 16) & 1u)) >> 16;
}
__device__ inline unsigned packbf(float lo, float hi) {
    return f2bf1(lo) | (f2bf1(hi) << 16);
}

// ---------------- k1: fused gather + conv + MFMA GEMM + partial sums ----------------
// Round-6 structure; gather software-pipelined 1 deep. (256,4): do NOT raise —
// (256,8) capped VGPR at 32 and spilled acc[] to scratch (round 8: WRITE 319MB).
__global__ __launch_bounds__(256, 4) void k1_fused(
    const float* __restrict__ xyz,       // [3,P]
    const float* __restrict__ feats,     // [CIN,P,NA]
    const int*   __restrict__ inter_idx, // [P,NN]
    const float* __restrict__ anchors,   // [NA,3,3]
    const float* __restrict__ kern,      // [KS,3]
    const float* __restrict__ W,         // [COUT,CK]
    float* __restrict__ out,             // [COUT,PA]  pre-norm
    float* __restrict__ psum,            // [COUT,PP]
    float* __restrict__ psq)             // [COUT,PP]
{
    const int p      = blockIdx.x;
    const int tid    = threadIdx.x;
    const int g      = tid >> 6;          // wave 0..3
    const int l      = tid & 63;
    const int lane15 = l & 15;
    const int quad   = l >> 4;
    const bool valid = (l < NA);
    const int  a     = valid ? l : (NA - 1);

    __shared__ float4 s_rel[NN];
    __shared__ int    s_idx[NN];
    __shared__ unsigned short s_fk[64 * FKLD];   // 17408 B

    // ---- phase A: neighbor relative coords ----
    if (tid < NN) {
        int j = inter_idx[p * NN + tid];
        s_idx[tid] = j;
        float rx = xyz[j]          - xyz[p];
        float ry = xyz[PP + j]     - xyz[PP + p];
        float rz = xyz[2 * PP + j] - xyz[2 * PP + p];
        s_rel[tid] = make_float4(rx, ry, rz, rx * rx + ry * ry + rz * rz);
    }

    // ---- phase B: per-thread rotated-kernel constants for anchor a ----
    float Cw[KS], Rx[KS], Ry[KS], Rz[KS];
    {
        const float* A = anchors + a * 9;
        float a00 = A[0], a01 = A[1], a02 = A[2];
        float a10 = A[3], a11 = A[4], a12 = A[5];
        float a20 = A[6], a21 = A[7], a22 = A[8];
        #pragma unroll
        for (int k = 0; k < KS; ++k) {
            float kx = kern[k * 3 + 0], ky = kern[k * 3 + 1], kz = kern[k * 3 + 2];
            float r0 = a00 * kx + a01 * ky + a02 * kz;
            float r1 = a10 * kx + a11 * ky + a12 * kz;
            float r2 = a20 * kx + a21 * ky + a22 * kz;
            Cw[k] = 1.0f - SIGMA_INV * (r0 * r0 + r1 * r1 + r2 * r2);
            Rx[k] = 2.0f * SIGMA_INV * r0;
            Ry[k] = 2.0f * SIGMA_INV * r1;
            Rz[k] = 2.0f * SIGMA_INV * r2;
        }
    }
    __syncthreads();

    // ---- phase D: fk[c,k] accumulation; gather software-pipelined 1 deep ----
    const float* fbase = feats + (size_t)(g * 8) * PA + a;

    float acc[8][KS];
    #pragma unroll
    for (int c = 0; c < 8; ++c)
        #pragma unroll
        for (int k = 0; k < KS; ++k) acc[c][k] = 0.0f;

    float fcur[8];
    {
        const float* fb = fbase + (size_t)s_idx[0] * NA;
        #pragma unroll
        for (int c = 0; c < 8; ++c)
            fcur[c] = fb[(size_t)c * PA];     // 60 consecutive lanes -> 240B coalesced
    }

    #pragma unroll
    for (int n = 0; n < NN; ++n) {
        float fnxt[8];
        if (n + 1 < NN) {
            const float* fb = fbase + (size_t)s_idx[n + 1] * NA;
            #pragma unroll
            for (int c = 0; c < 8; ++c)
                fnxt[c] = fb[(size_t)c * PA];  // issued before fcur is consumed
        }
        float4 rel = s_rel[n];
        float tb = -SIGMA_INV * rel.w;
        float w[KS];
        #pragma unroll
        for (int k = 0; k < KS; ++k) {
            float v = Cw[k] + tb;
            v = fmaf(rel.x, Rx[k], v);
            v = fmaf(rel.y, Ry[k], v);
            v = fmaf(rel.z, Rz[k], v);
            w[k] = v > 0.0f ? v : 0.0f;
        }
        #pragma unroll
        for (int c = 0; c < 8; ++c)
            #pragma unroll
            for (int k = 0; k < KS; ++k)
                acc[c][k] = fmaf(fcur[c], w[k], acc[c][k]);
        #pragma unroll
        for (int c = 0; c < 8; ++c) fcur[c] = fnxt[c];
    }

    // ---- pack to bf16, stage in LDS: s_fk[row=a][col=ck] ----
    {
        unsigned pk[16];
        #pragma unroll
        for (int c = 0; c < 8; ++c) {
            pk[c * 2 + 0] = valid ? packbf(acc[c][0], acc[c][1]) : 0u;
            pk[c * 2 + 1] = valid ? packbf(acc[c][2], acc[c][3]) : 0u;
        }
        uint4* dst = (uint4*)&s_fk[(size_t)l * FKLD + g * 32];
        dst[0] = make_uint4(pk[0],  pk[1],  pk[2],  pk[3]);
        dst[1] = make_uint4(pk[4],  pk[5],  pk[6],  pk[7]);
        dst[2] = make_uint4(pk[8],  pk[9],  pk[10], pk[11]);
        dst[3] = make_uint4(pk[12], pk[13], pk[14], pk[15]);
    }

    // ---- W rows -> bf16 A-fragments (after acc is dead: low register overlap) ----
    short8 afrag[4];
    {
        const float* wbase = W + (size_t)(g * 16 + lane15) * CK + quad * 8;
        #pragma unroll
        for (int ks = 0; ks < 4; ++ks) {
            float4 w0 = *(const float4*)(wbase + ks * 32);
            float4 w1 = *(const float4*)(wbase + ks * 32 + 4);
            union { short8 s; unsigned u[4]; } pa;
            pa.u[0] = packbf(w0.x, w0.y);
            pa.u[1] = packbf(w0.z, w0.w);
            pa.u[2] = packbf(w1.x, w1.y);
            pa.u[3] = packbf(w1.z, w1.w);
            afrag[ks] = pa.s;
        }
    }

    __syncthreads();

    // ---- phase E: MFMA  C[d, a] = sum_ck W[d,ck] * fk[a,ck] ----
    floatx4 cacc[4];
    #pragma unroll
    for (int t = 0; t < 4; ++t) cacc[t] = (floatx4){0.f, 0.f, 0.f, 0.f};

    #pragma unroll
    for (int ks = 0; ks < 4; ++ks) {
        #pragma unroll
        for (int t = 0; t < 4; ++t) {
            short8 bfrag = *(const short8*)&s_fk[(size_t)(t * 16 + lane15) * FKLD + ks * 32 + quad * 8];
            cacc[t] = __builtin_amdgcn_mfma_f32_16x16x32_bf16(afrag[ks], bfrag, cacc[t], 0, 0, 0);
        }
    }

    // ---- epilogue: store pre-norm out + per-(d,p) partial sums ----
    const int d0 = g * 16;
    float ssum[4] = {0.f, 0.f, 0.f, 0.f}, ssq[4] = {0.f, 0.f, 0.f, 0.f};
    #pragma unroll
    for (int t = 0; t < 4; ++t) {
        int acol = t * 16 + lane15;
        bool vcol = acol < NA;
        #pragma unroll
        for (int r = 0; r < 4; ++r) {
            float v = cacc[t][r];
            int d = d0 + quad * 4 + r;
            if (vcol) out[(size_t)d * PA + (size_t)p * NA + acol] = v;
            ssum[r] += v;   // padded cols are exact zeros
            ssq[r]  += v * v;
        }
    }
    #pragma unroll
    for (int r = 0; r < 4; ++r) {
        float ss = ssum[r], qq = ssq[r];
        #pragma unroll
        for (int off = 8; off; off >>= 1) {
            ss += __shfl_down(ss, off, 16);
            qq += __shfl_down(qq, off, 16);
        }
        if (lane15 == 0) {
            int d = d0 + quad * 4 + r;
            psum[d * PP + p] = ss;
            psq [d * PP + p] = qq;
        }
    }
}

// ---------------- k3: redundant per-channel stats + normalize + relu ----------------
// grid (60, 64): blockIdx.y = d, blockIdx.x = chunk of 1024 elements
__global__ __launch_bounds__(256) void k3_norm(
    const float* __restrict__ psum, const float* __restrict__ psq,
    float* __restrict__ out)
{
    const int d   = blockIdx.y;
    const int tid = threadIdx.x;

    // redundant reduction of this channel's 1024 partials (8 KB, L2-hot)
    float4 ps = ((const float4*)(psum + (size_t)d * PP))[tid];
    float4 qs = ((const float4*)(psq  + (size_t)d * PP))[tid];
    float s = ps.x + ps.y + ps.z + ps.w;
    float q = qs.x + qs.y + qs.z + qs.w;
    #pragma unroll
    for (int off = 32; off; off >>= 1) {
        s += __shfl_down(s, off, 64);
        q += __shfl_down(q, off, 64);
    }
    __shared__ float sred[8];
    __shared__ float s_mu, s_rs;
    int w = tid >> 6;
    if ((tid & 63) == 0) { sred[w] = s; sred[4 + w] = q; }
    __syncthreads();
    if (tid == 0) {
        float S = sred[0] + sred[1] + sred[2] + sred[3];
        float Q = sred[4] + sred[5] + sred[6] + sred[7];
        const float inv = 1.0f / (float)PA;
        float mu  = S * inv;
        float var = Q * inv - mu * mu;
        s_mu = mu;
        s_rs = rsqrtf(var + EPS);
    }
    __syncthreads();
    const float mu = s_mu, rs = s_rs;

    // normalize this block's 1024-element chunk (float4)
    size_t base = (size_t)d * PA + (size_t)blockIdx.x * 1024 + tid * 4;
    float4* po = (float4*)(out + base);
    float4 v = *po;
    v.x = fmaxf((v.x - mu) * rs, 0.f);
    v.y = fmaxf((v.y - mu) * rs, 0.f);
    v.z = fmaxf((v.z - mu) * rs, 0.f);
    v.w = fmaxf((v.w - mu) * rs, 0.f);
    *po = v;
}

extern "C" void kernel_launch(void* const* d_in, const int* in_sizes, int n_in,
                              void* d_out, int out_size, void* d_ws, size_t ws_size,
                              hipStream_t stream) {
    const float* xyz     = (const float*)d_in[0];
    const float* feats   = (const float*)d_in[1];
    const int*   idx     = (const int*)d_in[2];
    const float* anchors = (const float*)d_in[3];
    const float* kern    = (const float*)d_in[4];
    const float* W       = (const float*)d_in[5];
    float* out = (float*)d_out;

    float* ws   = (float*)d_ws;
    float* psum = ws;                 // 65,536 f
    float* psq  = psum + COUT * PP;   // 65,536 f

    hipLaunchKernelGGL(k1_fused, dim3(PP), dim3(256), 0, stream,
                       xyz, feats, idx, anchors, kern, W, out, psum, psq);
    hipLaunchKernelGGL(k3_norm, dim3(PA / 1024, COUT), dim3(256), 0, stream,
                       psum, psq, out);
}

// Round 10
// 98.824 us; speedup vs baseline: 6.4209x; 6.4209x over previous
//
#include <hip/hip_runtime.h>

#define CIN  32
#define COUT 64
#define PP   1024
#define NN   24
#define NA   60
#define KS   4
#define PA   (PP*NA)          // 61440
#define CK   (CIN*KS)         // 128
#define FKLD 136              // padded LDS row stride in shorts (272 B)
constexpr float SIGMA_INV = 12.5f;   // 1/0.08
constexpr float EPS = 1e-5f;

typedef __attribute__((ext_vector_type(8))) short short8;
typedef __attribute__((ext_vector_type(4))) float floatx4;

__device__ inline unsigned f2bf1(float f) {   // RTNE to bf16, as unsigned
    unsigned u = __float_as_uint(f);
    return (u + 0x7fffu + ((u >> 16) & 1u)) >> 16;
}
__device__ inline unsigned packbf(float lo, float hi) {
    return f2bf1(lo) | (f2bf1(hi) << 16);
}

// ---------------- k0: feats [CIN,P,NA] fp32 -> ftb [P,NA,CIN] bf16 ----------------
// Read coalesced (a contiguous), stage in LDS, write coalesced (linear row).
__global__ __launch_bounds__(256) void k0_cvt(
    const float* __restrict__ feats, unsigned short* __restrict__ ftb)
{
    const int p = blockIdx.x;
    __shared__ unsigned short s_t[CIN * NA];    // 3840 B, [a][c]
    for (int i = threadIdx.x; i < CIN * NA; i += 256) {
        int c = i / NA, a = i - c * NA;         // consecutive tid -> consecutive a
        s_t[a * CIN + c] = (unsigned short)f2bf1(feats[(size_t)c * PA + (size_t)p * NA + a]);
    }
    __syncthreads();
    const unsigned short* src = s_t;
    unsigned short* dst = ftb + (size_t)p * NA * CIN;
    // linear coalesced copy, 4B per thread per step
    const unsigned* s4 = (const unsigned*)src;
    unsigned* d4 = (unsigned*)dst;
    for (int i = threadIdx.x; i < CIN * NA / 2; i += 256) d4[i] = s4[i];
}

// ---------------- k1: fused gather + conv + MFMA GEMM + partial sums ----------------
// Round-6 structure; gather from bf16 ftb (L2-resident, 16B/lane per neighbor).
// NOTE: no 2nd launch_bounds arg — (256,8)/(256,4) caused VGPR caps + spills (r8/r9).
__global__ __launch_bounds__(256) void k1_fused(
    const float* __restrict__ xyz,       // [3,P]
    const unsigned short* __restrict__ ftb, // [P,NA,CIN] bf16
    const int*   __restrict__ inter_idx, // [P,NN]
    const float* __restrict__ anchors,   // [NA,3,3]
    const float* __restrict__ kern,      // [KS,3]
    const float* __restrict__ W,         // [COUT,CK]
    float* __restrict__ out,             // [COUT,PA]  pre-norm
    float* __restrict__ psum,            // [COUT,PP]
    float* __restrict__ psq)             // [COUT,PP]
{
    const int p      = blockIdx.x;
    const int tid    = threadIdx.x;
    const int g      = tid >> 6;          // wave 0..3
    const int l      = tid & 63;
    const int lane15 = l & 15;
    const int quad   = l >> 4;
    const bool valid = (l < NA);
    const int  a     = valid ? l : (NA - 1);

    __shared__ float4 s_rel[NN];
    __shared__ int    s_idx[NN];
    __shared__ unsigned short s_fk[64 * FKLD];   // 17408 B

    // ---- phase A: neighbor relative coords ----
    if (tid < NN) {
        int j = inter_idx[p * NN + tid];
        s_idx[tid] = j;
        float rx = xyz[j]          - xyz[p];
        float ry = xyz[PP + j]     - xyz[PP + p];
        float rz = xyz[2 * PP + j] - xyz[2 * PP + p];
        s_rel[tid] = make_float4(rx, ry, rz, rx * rx + ry * ry + rz * rz);
    }

    // ---- phase B: per-thread rotated-kernel constants for anchor a ----
    float Cw[KS], Rx[KS], Ry[KS], Rz[KS];
    {
        const float* A = anchors + a * 9;
        float a00 = A[0], a01 = A[1], a02 = A[2];
        float a10 = A[3], a11 = A[4], a12 = A[5];
        float a20 = A[6], a21 = A[7], a22 = A[8];
        #pragma unroll
        for (int k = 0; k < KS; ++k) {
            float kx = kern[k * 3 + 0], ky = kern[k * 3 + 1], kz = kern[k * 3 + 2];
            float r0 = a00 * kx + a01 * ky + a02 * kz;
            float r1 = a10 * kx + a11 * ky + a12 * kz;
            float r2 = a20 * kx + a21 * ky + a22 * kz;
            Cw[k] = 1.0f - SIGMA_INV * (r0 * r0 + r1 * r1 + r2 * r2);
            Rx[k] = 2.0f * SIGMA_INV * r0;
            Ry[k] = 2.0f * SIGMA_INV * r1;
            Rz[k] = 2.0f * SIGMA_INV * r2;
        }
    }
    __syncthreads();

    // ---- phase D: fk[c,k] accumulation; one short8 (16B) per neighbor ----
    const unsigned short* fbase = ftb + (size_t)a * CIN + g * 8;

    float acc[8][KS];
    #pragma unroll
    for (int c = 0; c < 8; ++c)
        #pragma unroll
        for (int k = 0; k < KS; ++k) acc[c][k] = 0.0f;

    #pragma unroll 2
    for (int n = 0; n < NN; ++n) {
        float4 rel = s_rel[n];
        int j = s_idx[n];
        union { short8 s; unsigned u[4]; } fv;
        fv.s = *(const short8*)(fbase + (size_t)j * (NA * CIN));
        float tb = -SIGMA_INV * rel.w;
        float w[KS];
        #pragma unroll
        for (int k = 0; k < KS; ++k) {
            float v = Cw[k] + tb;
            v = fmaf(rel.x, Rx[k], v);
            v = fmaf(rel.y, Ry[k], v);
            v = fmaf(rel.z, Rz[k], v);
            w[k] = v > 0.0f ? v : 0.0f;
        }
        float f[8];
        #pragma unroll
        for (int q = 0; q < 4; ++q) {
            f[2 * q]     = __uint_as_float(fv.u[q] << 16);
            f[2 * q + 1] = __uint_as_float(fv.u[q] & 0xffff0000u);
        }
        #pragma unroll
        for (int c = 0; c < 8; ++c)
            #pragma unroll
            for (int k = 0; k < KS; ++k)
                acc[c][k] = fmaf(f[c], w[k], acc[c][k]);
    }

    // ---- pack to bf16, stage in LDS: s_fk[row=a][col=ck] ----
    {
        unsigned pk[16];
        #pragma unroll
        for (int c = 0; c < 8; ++c) {
            pk[c * 2 + 0] = valid ? packbf(acc[c][0], acc[c][1]) : 0u;
            pk[c * 2 + 1] = valid ? packbf(acc[c][2], acc[c][3]) : 0u;
        }
        uint4* dst = (uint4*)&s_fk[(size_t)l * FKLD + g * 32];
        dst[0] = make_uint4(pk[0],  pk[1],  pk[2],  pk[3]);
        dst[1] = make_uint4(pk[4],  pk[5],  pk[6],  pk[7]);
        dst[2] = make_uint4(pk[8],  pk[9],  pk[10], pk[11]);
        dst[3] = make_uint4(pk[12], pk[13], pk[14], pk[15]);
    }

    // ---- W rows -> bf16 A-fragments (after acc is dead: low register overlap) ----
    short8 afrag[4];
    {
        const float* wbase = W + (size_t)(g * 16 + lane15) * CK + quad * 8;
        #pragma unroll
        for (int ks = 0; ks < 4; ++ks) {
            float4 w0 = *(const float4*)(wbase + ks * 32);
            float4 w1 = *(const float4*)(wbase + ks * 32 + 4);
            union { short8 s; unsigned u[4]; } pa;
            pa.u[0] = packbf(w0.x, w0.y);
            pa.u[1] = packbf(w0.z, w0.w);
            pa.u[2] = packbf(w1.x, w1.y);
            pa.u[3] = packbf(w1.z, w1.w);
            afrag[ks] = pa.s;
        }
    }

    __syncthreads();

    // ---- phase E: MFMA  C[d, a] = sum_ck W[d,ck] * fk[a,ck] ----
    floatx4 cacc[4];
    #pragma unroll
    for (int t = 0; t < 4; ++t) cacc[t] = (floatx4){0.f, 0.f, 0.f, 0.f};

    #pragma unroll
    for (int ks = 0; ks < 4; ++ks) {
        #pragma unroll
        for (int t = 0; t < 4; ++t) {
            short8 bfrag = *(const short8*)&s_fk[(size_t)(t * 16 + lane15) * FKLD + ks * 32 + quad * 8];
            cacc[t] = __builtin_amdgcn_mfma_f32_16x16x32_bf16(afrag[ks], bfrag, cacc[t], 0, 0, 0);
        }
    }

    // ---- epilogue: store pre-norm out + per-(d,p) partial sums ----
    const int d0 = g * 16;
    float ssum[4] = {0.f, 0.f, 0.f, 0.f}, ssq[4] = {0.f, 0.f, 0.f, 0.f};
    #pragma unroll
    for (int t = 0; t < 4; ++t) {
        int acol = t * 16 + lane15;
        bool vcol = acol < NA;
        #pragma unroll
        for (int r = 0; r < 4; ++r) {
            float v = cacc[t][r];
            int d = d0 + quad * 4 + r;
            if (vcol) out[(size_t)d * PA + (size_t)p * NA + acol] = v;
            ssum[r] += v;   // padded cols are exact zeros
            ssq[r]  += v * v;
        }
    }
    #pragma unroll
    for (int r = 0; r < 4; ++r) {
        float ss = ssum[r], qq = ssq[r];
        #pragma unroll
        for (int off = 8; off; off >>= 1) {
            ss += __shfl_down(ss, off, 16);
            qq += __shfl_down(qq, off, 16);
        }
        if (lane15 == 0) {
            int d = d0 + quad * 4 + r;
            psum[d * PP + p] = ss;
            psq [d * PP + p] = qq;
        }
    }
}

// ---------------- k3: redundant per-channel stats + normalize + relu ----------------
// grid (60, 64): blockIdx.y = d, blockIdx.x = chunk of 1024 elements
__global__ __launch_bounds__(256) void k3_norm(
    const float* __restrict__ psum, const float* __restrict__ psq,
    float* __restrict__ out)
{
    const int d   = blockIdx.y;
    const int tid = threadIdx.x;

    // redundant reduction of this channel's 1024 partials (8 KB, L2-hot)
    float4 ps = ((const float4*)(psum + (size_t)d * PP))[tid];
    float4 qs = ((const float4*)(psq  + (size_t)d * PP))[tid];
    float s = ps.x + ps.y + ps.z + ps.w;
    float q = qs.x + qs.y + qs.z + qs.w;
    #pragma unroll
    for (int off = 32; off; off >>= 1) {
        s += __shfl_down(s, off, 64);
        q += __shfl_down(q, off, 64);
    }
    __shared__ float sred[8];
    __shared__ float s_mu, s_rs;
    int w = tid >> 6;
    if ((tid & 63) == 0) { sred[w] = s; sred[4 + w] = q; }
    __syncthreads();
    if (tid == 0) {
        float S = sred[0] + sred[1] + sred[2] + sred[3];
        float Q = sred[4] + sred[5] + sred[6] + sred[7];
        const float inv = 1.0f / (float)PA;
        float mu  = S * inv;
        float var = Q * inv - mu * mu;
        s_mu = mu;
        s_rs = rsqrtf(var + EPS);
    }
    __syncthreads();
    const float mu = s_mu, rs = s_rs;

    // normalize this block's 1024-element chunk (float4)
    size_t base = (size_t)d * PA + (size_t)blockIdx.x * 1024 + tid * 4;
    float4* po = (float4*)(out + base);
    float4 v = *po;
    v.x = fmaxf((v.x - mu) * rs, 0.f);
    v.y = fmaxf((v.y - mu) * rs, 0.f);
    v.z = fmaxf((v.z - mu) * rs, 0.f);
    v.w = fmaxf((v.w - mu) * rs, 0.f);
    *po = v;
}

extern "C" void kernel_launch(void* const* d_in, const int* in_sizes, int n_in,
                              void* d_out, int out_size, void* d_ws, size_t ws_size,
                              hipStream_t stream) {
    const float* xyz     = (const float*)d_in[0];
    const float* feats   = (const float*)d_in[1];
    const int*   idx     = (const int*)d_in[2];
    const float* anchors = (const float*)d_in[3];
    const float* kern    = (const float*)d_in[4];
    const float* W       = (const float*)d_in[5];
    float* out = (float*)d_out;

    float* ws = (float*)d_ws;
    unsigned short* ftb = (unsigned short*)ws;           // P*NA*CIN bf16 = 3.93 MB
    float* psum = (float*)(ftb + (size_t)PP * NA * CIN); // 65,536 f
    float* psq  = psum + COUT * PP;                      // 65,536 f

    hipLaunchKernelGGL(k0_cvt, dim3(PP), dim3(256), 0, stream, feats, ftb);
    hipLaunchKernelGGL(k1_fused, dim3(PP), dim3(256), 0, stream,
                       xyz, ftb, idx, anchors, kern, W, out, psum, psq);
    hipLaunchKernelGGL(k3_norm, dim3(PA / 1024, COUT), dim3(256), 0, stream,
                       psum, psq, out);
}